// Round 3
// baseline (205.856 us; speedup 1.0000x reference)
//
#include <hip/hip_runtime.h>
#include <hip/hip_bf16.h>

// PROBE ROUND: run the streaming body TWICE (idempotent) to measure the true
// kernel duration differentially through the harness-overhead-dominated dur_us.
// Pass-2 addresses are offset by an opaque runtime zero (inline asm) so the
// compiler cannot CSE the loads or DCE the pass.
//
// out[r] = sum_i cos(x[r][i]) * w[i] + b   (theta unused)

#define BATCH 1048576
#define WIRES 32
#define BLOCK 256
#define GRID  2048
#define TOTAL_THREADS (GRID * BLOCK)            // 524288, multiple of 8
#define TOTAL_F4 (BATCH * (WIRES / 4))          // 8388608
#define ITERS (TOTAL_F4 / TOTAL_THREADS)        // 16

__global__ __launch_bounds__(BLOCK) void hybrid_regression_kernel(
    const float4* __restrict__ x4,   // BATCH*8 float4s
    const float*  __restrict__ w,    // 32 floats
    const float*  __restrict__ bias, // 1 float
    float*        __restrict__ out)  // BATCH floats
{
    const int t   = blockIdx.x * BLOCK + threadIdx.x;
    const int seg = threadIdx.x & 7;               // quarter-of-row, loop-invariant

    const float4 wv = ((const float4*)w)[seg];
    const float  bb = bias[0];

    // Opaque zero: compiler must assume it's unknown, so pass-2 loads can't be
    // CSE'd against pass-1 loads (runtime value is 0 -> same addresses, correct).
    int zoff;
    asm volatile("v_mov_b32 %0, 0" : "=v"(zoff));

    for (int pass = 0; pass < 2; ++pass) {
        const int po = pass * zoff;                // 0 at runtime, opaque
#pragma unroll 4
        for (int i = 0; i < ITERS; ++i) {
            const int fi = t + i * TOTAL_THREADS;  // true float4 index
            const float4 v = x4[fi + po];          // opaque address for pass 2

            float p = __cosf(v.x) * wv.x
                    + __cosf(v.y) * wv.y
                    + __cosf(v.z) * wv.z
                    + __cosf(v.w) * wv.w;

            p += __shfl_down(p, 4, 8);
            p += __shfl_down(p, 2, 8);
            p += __shfl_down(p, 1, 8);

            if (seg == 0) {
                out[fi >> 3] = p + bb;             // idempotent across passes
            }
        }
    }
}

extern "C" void kernel_launch(void* const* d_in, const int* in_sizes, int n_in,
                              void* d_out, int out_size, void* d_ws, size_t ws_size,
                              hipStream_t stream) {
    const float* x    = (const float*)d_in[0];
    // d_in[1] = theta, unused (RZ phase does not affect <Z>)
    const float* w    = (const float*)d_in[2];
    const float* bias = (const float*)d_in[3];
    float* out        = (float*)d_out;

    hybrid_regression_kernel<<<GRID, BLOCK, 0, stream>>>(
        (const float4*)x, w, bias, out);
}

// Round 4
// 186.042 us; speedup vs baseline: 1.1065x; 1.1065x over previous
//
#include <hip/hip_runtime.h>
#include <hip/hip_bf16.h>

// out[r] = sum_i cos(x[r][i]) * w[i] + b   (theta unused; RZ leaves <Z> invariant)
// B = 1048576 rows, W = 32 cols. Pure streaming, memory-bound.
//
// ROOFLINE EVIDENCE (R3 probe): running this body twice cost only +14.7 us,
// so one pass ~15-20 us = 132 MiB / ~6.9 TB/s — at the achievable HBM ceiling
// (harness fills measure 6.95-7.0 TB/s on this device). dur_us ~187 is
// dominated by ~170 us of harness restore/poison traffic.
//
// Mapping: 8 lanes per row, each lane loads one float4 (16B); global float4
// index == global thread id -> perfectly coalesced 1 KiB/wave-instr.
// Width-8 shuffle reduce, lane seg==0 writes the row result.

#define BATCH 1048576
#define WIRES 32

__global__ __launch_bounds__(256) void hybrid_regression_kernel(
    const float4* __restrict__ x4,   // BATCH*8 float4s
    const float*  __restrict__ w,    // 32 floats
    const float*  __restrict__ bias, // 1 float
    float*        __restrict__ out)  // BATCH floats
{
    const int tid = blockIdx.x * 256 + threadIdx.x;   // 0 .. BATCH*8-1
    const int seg = threadIdx.x & 7;                  // which quarter-of-row

    const float4 v  = x4[tid];
    const float4 wv = ((const float4*)w)[seg];

    float p = __cosf(v.x) * wv.x
            + __cosf(v.y) * wv.y
            + __cosf(v.z) * wv.z
            + __cosf(v.w) * wv.w;

    // reduce across the 8 lanes covering this row
    p += __shfl_down(p, 4, 8);
    p += __shfl_down(p, 2, 8);
    p += __shfl_down(p, 1, 8);

    if (seg == 0) {
        out[tid >> 3] = p + bias[0];
    }
}

extern "C" void kernel_launch(void* const* d_in, const int* in_sizes, int n_in,
                              void* d_out, int out_size, void* d_ws, size_t ws_size,
                              hipStream_t stream) {
    const float* x    = (const float*)d_in[0];
    // d_in[1] = theta, unused (RZ phase does not affect <Z>)
    const float* w    = (const float*)d_in[2];
    const float* bias = (const float*)d_in[3];
    float* out        = (float*)d_out;

    const int total_threads = BATCH * (WIRES / 4);    // 8,388,608
    const int block = 256;
    const int grid  = total_threads / block;          // 32,768

    hybrid_regression_kernel<<<grid, block, 0, stream>>>(
        (const float4*)x, w, bias, out);
}